// Round 1
// baseline (399.400 us; speedup 1.0000x reference)
//
#include <hip/hip_runtime.h>

// y[n] = x[n] + ALPHA * y[n-1], zero init, per row. 64 rows x 960000 fp32.
// Chunked parallel scan: alpha^256 ~ 8.7e-19 => 256-sample warm-up lookback
// makes chunks independent to well below fp32 precision.
//
// Layout v2: LANE-INTERLEAVED float4. Lane l owns elements [4l, 4l+4) of a
// 256-element "group"; each wave processes G=4 groups (1024 elems); 4 waves
// per block -> 4096-element window, 3840-output chunk (250 chunks/row exact).
// All global loads/stores are fully coalesced (1 KB per wave instruction),
// unlike the previous per-thread-contiguous T=16 layout (64B-strided lanes).

#define ALPHA 0.85f

constexpr int ROW    = 960000;
constexpr int BT     = 256;            // threads per block = 4 waves
constexpr int WAVES  = BT / 64;
constexpr int G      = 4;              // float4 groups per wave
constexpr int GELEM  = 256;            // elements per group (64 lanes * 4)
constexpr int WELEM  = G * GELEM;      // 1024 elements per wave
constexpr int TOT    = WAVES * WELEM;  // 4096-element window
constexpr int LOOK   = 256;            // warm-up lookback = exactly one group
constexpr int CHUNK  = TOT - LOOK;     // 3840 outputs per block
constexpr int CHUNKS = ROW / CHUNK;    // 250 (exact: 960000 = 250*3840)

// alpha^n at compile time (double accumulate, cast to float).
constexpr float apow(int n) {
    double r = 1.0;
    for (int i = 0; i < n; ++i) r *= 0.85;
    return (float)r;
}

constexpr float A1    = apow(1);
constexpr float A2    = apow(2);
constexpr float A3    = apow(3);
constexpr float A4    = apow(4);
constexpr float A8    = apow(8);
constexpr float A16   = apow(16);
constexpr float A32   = apow(32);
constexpr float A64   = apow(64);
constexpr float A128  = apow(128);
constexpr float A256  = apow(256);     // ~8.7e-19: cross-group carry weight
constexpr float A1024 = apow(1024);    // underflows to 0.0f -- fine
constexpr float LOG2_A4 = -0.9378610145f;  // 4 * log2(0.85)

__global__ __launch_bounds__(BT) void deemph_kernel(const float* __restrict__ x,
                                                    float* __restrict__ y) {
    const int blk  = blockIdx.x;
    const int r    = blk / CHUNKS;
    const int c    = blk - r * CHUNKS;
    const int t    = threadIdx.x;
    const int lane = t & 63;
    const int wave = t >> 6;

    // window element 0 = chunk start - LOOK
    const long long winbase = (long long)r * ROW + (long long)c * CHUNK - LOOK;
    const int woff0 = wave * WELEM + 4 * lane;   // window offset of lane's group-0 quad

    // ---- coalesced loads: G groups per wave (lane-interleaved float4).
    // Warm-up group (window [0,256) == wave 0, g 0) of chunk 0 is pre-row: zeros
    // (and for r==0 would be OOB -- must not issue the load).
    const bool warm0 = (c == 0) && (wave == 0);
    float4 q[G];
    #pragma unroll
    for (int g = 0; g < G; ++g) {
        if (g == 0 && warm0) {
            q[0] = make_float4(0.f, 0.f, 0.f, 0.f);
        } else {
            q[g] = *(const float4*)(x + winbase + woff0 + g * GELEM);
        }
    }

    // ---- in-lane serial scan of 4 elements (zero init), keep per-elem values
    float v0[G], v1[G], v2[G], v3[G], acc[G];
    #pragma unroll
    for (int g = 0; g < G; ++g) {
        float s;
        s = q[g].x;             v0[g] = s;
        s = q[g].y + ALPHA * s; v1[g] = s;
        s = q[g].z + ALPHA * s; v2[g] = s;
        s = q[g].w + ALPHA * s; v3[g] = s;
        acc[g] = s;             // lane segment sum (state after 4 elems, zero-in)
    }

    // ---- weighted Kogge-Stone inclusive scan across lanes, per group.
    // 4 independent 6-step chains -> compiler can interleave for latency.
    #pragma unroll
    for (int g = 0; g < G; ++g) {
        float up;
        up = __shfl_up(acc[g], 1, 64);  if (lane >= 1)  acc[g] += A4   * up;
        up = __shfl_up(acc[g], 2, 64);  if (lane >= 2)  acc[g] += A8   * up;
        up = __shfl_up(acc[g], 4, 64);  if (lane >= 4)  acc[g] += A16  * up;
        up = __shfl_up(acc[g], 8, 64);  if (lane >= 8)  acc[g] += A32  * up;
        up = __shfl_up(acc[g], 16, 64); if (lane >= 16) acc[g] += A64  * up;
        up = __shfl_up(acc[g], 32, 64); if (lane >= 32) acc[g] += A128 * up;
    }

    // ---- group totals (state after 256 elems, zero-in) + exclusive per-lane
    float T[G], ex[G];
    #pragma unroll
    for (int g = 0; g < G; ++g) {
        T[g] = __shfl(acc[g], 63, 64);
        float e = __shfl_up(acc[g], 1, 64);
        ex[g] = (lane == 0) ? 0.0f : e;
    }

    // wave total: chain the 4 group totals
    const float WT = ((T[0] * A256 + T[1]) * A256 + T[2]) * A256 + T[3];

    // ---- cross-wave combine (4 waves)
    __shared__ float wsum[WAVES];
    if (lane == 0) wsum[wave] = WT;
    __syncthreads();
    float W = 0.0f;                          // state at start of this wave
    for (int w2 = 0; w2 < wave; ++w2) W = wsum[w2] + A1024 * W;

    // state at start of each group
    float S[G];
    S[0] = W;
    #pragma unroll
    for (int g = 1; g < G; ++g) S[g] = T[g-1] + A256 * S[g-1];

    // propagate group-start state through 4*lane elements
    const float al4 = exp2f((float)lane * LOG2_A4);

    // ---- apply prefix + coalesced stores. Window [0,256) (wave 0, g 0) is the
    // lookback region: never stored (it belongs to the previous chunk).
    #pragma unroll
    for (int g = 0; g < G; ++g) {
        if (g == 0 && wave == 0) continue;
        const float P = ex[g] + al4 * S[g];  // state just before this lane's quad
        float4 o;
        o.x = v0[g] + A1 * P;
        o.y = v1[g] + A2 * P;
        o.z = v2[g] + A3 * P;
        o.w = v3[g] + A4 * P;
        *(float4*)(y + winbase + woff0 + g * GELEM) = o;
    }
}

extern "C" void kernel_launch(void* const* d_in, const int* in_sizes, int n_in,
                              void* d_out, int out_size, void* d_ws, size_t ws_size,
                              hipStream_t stream) {
    const float* x = (const float*)d_in[0];
    float* y = (float*)d_out;
    const int nrows = in_sizes[0] / ROW;     // 64
    deemph_kernel<<<dim3(nrows * CHUNKS), dim3(BT), 0, stream>>>(x, y);
}